// Round 7
// baseline (785.692 us; speedup 1.0000x reference)
//
#include <hip/hip_runtime.h>
#include <hip/hip_bf16.h>

#define HID 512
#define NH  8
#define DD  64
#define GG  64
#define EPSF 1e-5f

typedef __attribute__((ext_vector_type(8))) short short8;
typedef __attribute__((ext_vector_type(4))) short short4v;
typedef __attribute__((ext_vector_type(4))) float floatx4;

__device__ __forceinline__ short f2bf(float f) {
    union { float f; unsigned u; } v; v.f = f;
    unsigned r = v.u + 0x7fffu + ((v.u >> 16) & 1u);
    return (short)(r >> 16);
}

#define GLOAD_LDS16(g, l) __builtin_amdgcn_global_load_lds( \
    (const __attribute__((address_space(1))) unsigned int*)(g), \
    (__attribute__((address_space(3))) unsigned int*)(l), 16, 0, 0)

// ---------------------------------------------------------------------------
// fold1: Wcat (1024x512 bf16) = [Wfx ; temp[h] * (Ws @ Wx_head)]
//        bias_cat (1024 f32)  = [bfx ; temp[h] * (Ws @ bx_head + bs)]
// ---------------------------------------------------------------------------
__global__ void fold1_kernel(const float* __restrict__ Wx, const float* __restrict__ bx,
                             const float* __restrict__ Wfx, const float* __restrict__ bfx,
                             const float* __restrict__ Ws, const float* __restrict__ bs,
                             const float* __restrict__ temp,
                             short* __restrict__ Wcat, float* __restrict__ bias_cat) {
    int idx = blockIdx.x * 256 + threadIdx.x;   // 0 .. 1024*512-1
    int row = idx >> 9;
    int k = idx & 511;
    float val;
    if (row < 512) {
        val = Wfx[row * 512 + k];
        if (k == 0) bias_cat[row] = bfx[row];
    } else {
        int hg = row - 512;
        int h = hg >> 6, g = hg & 63;
        float t = temp[h];
        float s = 0.f;
        #pragma unroll 8
        for (int d = 0; d < 64; ++d) s += Ws[g * 64 + d] * Wx[(h * 64 + d) * 512 + k];
        val = s * t;
        if (k == 0) {
            float b = 0.f;
            for (int d = 0; d < 64; ++d) b += Ws[g * 64 + d] * bx[h * 64 + d];
            bias_cat[row] = (b + bs[g]) * t;
        }
    }
    Wcat[idx] = f2bf(val);
}

// ---------------------------------------------------------------------------
// gemm1_pool: fused {cast + x@Wcat^T + bias + softmax + POOL}.
// Block = 128 rows x 256 cols, where the 256 cols are the fx-cols AND the
// w-cols of head pair {2c, 2c+1}  (B panel rows [c*128,+128) and
// [512+c*128,+128) of Wcat). 512 threads = 8 waves (2 row x 4 col); waves
// wn=0,1 own fx cols, wn=2,3 own w cols (one head's 64-g range each, so the
// existing 16-lane softmax reduce applies unchanged).
//
// After the K loop + in-place epilogue (bias / softmax):
//   - w is written to global w_bf (N x 512, dense);  fx is NEVER written.
//   - Per head hp: both operands are staged TRANSPOSED into LDS
//     (wT[g][n], fxT[d][n], pad 136 shorts -> 2-way banks, b64 writes),
//     zeroing rows >= M; then all 8 waves run the K=128 pool MFMA
//     tok[g,d] += w^T @ fx  (clean b128 frag reads) + a ones-MFMA for norm,
//     accumulated via f32 atomicAdd (split-K over row-tiles).
// Values staged are f2bf-quantized — identical to what pool_mfma read from
// mid before. A staging from f32 x: reg prefetch + f2bf + ds_write_b128
// (swizzled image, same as R6). B: global_load_lds width 16.
// ---------------------------------------------------------------------------
__global__ __launch_bounds__(512, 2)
void gemm1_pool(const float* __restrict__ X,       // (M x 512) f32
                const short* __restrict__ Wc,      // Wcat (1024 x 512) bf16
                const float* __restrict__ bias,    // 1024 f32
                short* __restrict__ Wb,            // w_bf out (M x 512) bf16
                float* __restrict__ tok_raw,       // 8*64*64 f32 (atomic)
                float* __restrict__ norm_,         // 8*64 f32 (atomic)
                int M, int Rtiles) {
    const int lda = 512;
    __shared__ short smem[24576];                  // 48 KiB
    short* As = smem;                              // 128*64
    short* Bs = smem + 8192;                       // 2 halves of 128*64

    const int id = blockIdx.x;
    const int xcd = id & 7;
    const int s = id >> 3;
    const int cblk = s & 3;                        // head-pair 0..3
    const int slice = (Rtiles + 7) >> 3;
    const int rt = xcd * slice + (s >> 2);
    if (rt >= Rtiles) return;

    const int tid = threadIdx.x;
    const int wid = tid >> 6, lane = tid & 63;
    const int wm = wid >> 2, wn = wid & 3;         // 2 x 4 wave grid
    const int lr = lane & 15, lq = lane >> 4;
    const int row0 = rt * 128;

    // staging maps (c = tid + it*512 in [0,1024); row = c>>3, swizzled chunk)
    int st_row[2], st_kc[2];
    const float* aptr[2];
    #pragma unroll
    for (int it = 0; it < 2; ++it) {
        int c = tid + it * 512;
        st_row[it] = c >> 3;
        st_kc[it] = (c & 7) ^ (st_row[it] & 7);
        int ar = min(row0 + st_row[it], M - 1);    // clamp phantom rows
        aptr[it] = X + (size_t)ar * lda + st_kc[it] * 8;
    }
    const short* Bb0 = Wc + (size_t)(cblk * 128) * lda;         // fx rows
    const short* Bb1 = Wc + (size_t)(512 + cblk * 128) * lda;   // w rows

    const int fx0 = (lq ^ (lr & 7)) * 8;
    const int fx1 = ((4 + lq) ^ (lr & 7)) * 8;

    floatx4 acc[4][4];
    #pragma unroll
    for (int i = 0; i < 4; ++i)
        #pragma unroll
        for (int j = 0; j < 4; ++j) acc[i][j] = (floatx4)(0.f);

    // prologue: prefetch A regs for k0 = 0
    float4 fa[2][2];
    #pragma unroll
    for (int it = 0; it < 2; ++it) {
        fa[it][0] = *(const float4*)(aptr[it]);
        fa[it][1] = *(const float4*)(aptr[it] + 4);
    }

    for (int k0 = 0; k0 < 512; k0 += 64) {
        // B: both halves via gload_lds (latency overlaps cvt VALU)
        #pragma unroll
        for (int it = 0; it < 2; ++it) {
            short* d0 = Bs +        (it * 512 + wid * 64) * 8;
            short* d1 = Bs + 8192 + (it * 512 + wid * 64) * 8;
            GLOAD_LDS16(Bb0 + (size_t)st_row[it] * lda + k0 + st_kc[it] * 8, d0);
            GLOAD_LDS16(Bb1 + (size_t)st_row[it] * lda + k0 + st_kc[it] * 8, d1);
        }
        // A: convert current regs, write swizzled LDS image
        #pragma unroll
        for (int it = 0; it < 2; ++it) {
            short8 sv;
            sv[0] = f2bf(fa[it][0].x); sv[1] = f2bf(fa[it][0].y);
            sv[2] = f2bf(fa[it][0].z); sv[3] = f2bf(fa[it][0].w);
            sv[4] = f2bf(fa[it][1].x); sv[5] = f2bf(fa[it][1].y);
            sv[6] = f2bf(fa[it][1].z); sv[7] = f2bf(fa[it][1].w);
            *(short8*)&As[(size_t)(tid + it * 512) * 8] = sv;
        }
        __syncthreads();

        // prefetch next K-step's A regs (hides under MFMA)
        const int kn = (k0 + 64 < 512) ? (k0 + 64) : 0;
        #pragma unroll
        for (int it = 0; it < 2; ++it) {
            fa[it][0] = *(const float4*)(aptr[it] + kn);
            fa[it][1] = *(const float4*)(aptr[it] + kn + 4);
        }

        const int bbase = (wn >> 1) * 8192;
        short8 af[4], bfr[4];
        // kh = 0
        #pragma unroll
        for (int i = 0; i < 4; ++i) af[i]  = *(const short8*)&As[(wm * 64 + i * 16 + lr) * 64 + fx0];
        #pragma unroll
        for (int j = 0; j < 4; ++j) bfr[j] = *(const short8*)&Bs[bbase + ((wn & 1) * 64 + j * 16 + lr) * 64 + fx0];
        #pragma unroll
        for (int i = 0; i < 4; ++i)
            #pragma unroll
            for (int j = 0; j < 4; ++j)
                acc[i][j] = __builtin_amdgcn_mfma_f32_16x16x32_bf16(af[i], bfr[j], acc[i][j], 0, 0, 0);
        // kh = 1
        #pragma unroll
        for (int i = 0; i < 4; ++i) af[i]  = *(const short8*)&As[(wm * 64 + i * 16 + lr) * 64 + fx1];
        #pragma unroll
        for (int j = 0; j < 4; ++j) bfr[j] = *(const short8*)&Bs[bbase + ((wn & 1) * 64 + j * 16 + lr) * 64 + fx1];
        #pragma unroll
        for (int i = 0; i < 4; ++i)
            #pragma unroll
            for (int j = 0; j < 4; ++j)
                acc[i][j] = __builtin_amdgcn_mfma_f32_16x16x32_bf16(af[i], bfr[j], acc[i][j], 0, 0, 0);
        __syncthreads();
    }

    // --- in-place epilogue: bias, and softmax on w waves ---
    float bcol[4];
    const int cbase = (wn < 2) ? (cblk * 128 + wn * 64)
                               : (512 + cblk * 128 + (wn - 2) * 64);
    #pragma unroll
    for (int j = 0; j < 4; ++j) bcol[j] = bias[cbase + j * 16 + lr];

    if (wn >= 2) {
        #pragma unroll
        for (int i = 0; i < 4; ++i) {
            #pragma unroll
            for (int r = 0; r < 4; ++r) {
                float v[4];
                #pragma unroll
                for (int j = 0; j < 4; ++j) v[j] = acc[i][j][r] + bcol[j];
                float m = fmaxf(fmaxf(v[0], v[1]), fmaxf(v[2], v[3]));
                #pragma unroll
                for (int off = 1; off < 16; off <<= 1) m = fmaxf(m, __shfl_xor(m, off));
                float sum = 0.f;
                #pragma unroll
                for (int j = 0; j < 4; ++j) { v[j] = __expf(v[j] - m); sum += v[j]; }
                #pragma unroll
                for (int off = 1; off < 16; off <<= 1) sum += __shfl_xor(sum, off);
                const float inv = 1.f / sum;
                #pragma unroll
                for (int j = 0; j < 4; ++j) acc[i][j][r] = v[j] * inv;
            }
        }
        // store w to dense w_bf (col = head*64+g = cblk*128 + (wn-2)*64 + j*16+lr)
        #pragma unroll
        for (int i = 0; i < 4; ++i) {
            #pragma unroll
            for (int r = 0; r < 4; ++r) {
                const int grow = row0 + wm * 64 + i * 16 + lq * 4 + r;
                if (grow < M) {
                    #pragma unroll
                    for (int j = 0; j < 4; ++j)
                        Wb[(size_t)grow * 512 + cblk * 128 + (wn - 2) * 64 + j * 16 + lr] =
                            f2bf(acc[i][j][r]);
                }
            }
        }
    } else {
        #pragma unroll
        for (int i = 0; i < 4; ++i)
            #pragma unroll
            for (int j = 0; j < 4; ++j)
                #pragma unroll
                for (int r = 0; r < 4; ++r) acc[i][j][r] += bcol[j];
    }

    // --- pool passes: per head hp, stage transposed + K=128 MFMA + atomics ---
    short* wT  = smem;          // 64 x 136 shorts
    short* fxT = smem + 8704;   // 64 x 136 shorts
    short8 ones;
    #pragma unroll
    for (int j = 0; j < 8; ++j) ones[j] = (short)0x3F80;   // bf16 1.0
    const int head0 = cblk * 2;

    #pragma unroll 1
    for (int hp = 0; hp < 2; ++hp) {
        __syncthreads();   // previous smem use done
        if (wn == hp || wn == 2 + hp) {
            short* dst = (wn >= 2) ? wT : fxT;   // w -> wT[g][n], fx -> fxT[d][n]
            #pragma unroll
            for (int i = 0; i < 4; ++i) {
                #pragma unroll
                for (int j = 0; j < 4; ++j) {
                    short4v pk;
                    #pragma unroll
                    for (int r = 0; r < 4; ++r) {
                        const int grow = row0 + wm * 64 + i * 16 + lq * 4 + r;
                        pk[r] = (grow < M) ? f2bf(acc[i][j][r]) : (short)0;
                    }
                    *(short4v*)&dst[(j * 16 + lr) * 136 + wm * 64 + i * 16 + lq * 4] = pk;
                }
            }
        }
        __syncthreads();
        // pool MFMA: 16 frags over 8 waves (gi = wid>>1, dj pair = wid&1)
        const int gi = wid >> 1, djp = wid & 1;
        floatx4 pacc[2];
        pacc[0] = (floatx4)(0.f); pacc[1] = (floatx4)(0.f);
        floatx4 nacc = (floatx4)(0.f);
        #pragma unroll
        for (int ks = 0; ks < 4; ++ks) {
            short8 paf = *(const short8*)&wT[(gi * 16 + lr) * 136 + ks * 32 + lq * 8];
            #pragma unroll
            for (int t = 0; t < 2; ++t) {
                short8 pbf = *(const short8*)&fxT[((djp * 2 + t) * 16 + lr) * 136 + ks * 32 + lq * 8];
                pacc[t] = __builtin_amdgcn_mfma_f32_16x16x32_bf16(paf, pbf, pacc[t], 0, 0, 0);
            }
            if (djp == 0)
                nacc = __builtin_amdgcn_mfma_f32_16x16x32_bf16(paf, ones, nacc, 0, 0, 0);
        }
        const int head = head0 + hp;
        #pragma unroll
        for (int t = 0; t < 2; ++t)
            #pragma unroll
            for (int r = 0; r < 4; ++r)
                atomicAdd(&tok_raw[(head * 64 + gi * 16 + lq * 4 + r) * 64 + (djp * 2 + t) * 16 + lr],
                          pacc[t][r]);
        if (djp == 0 && lr == 0) {
            #pragma unroll
            for (int r = 0; r < 4; ++r)
                atomicAdd(&norm_[head * 64 + gi * 16 + lq * 4 + r], nacc[r]);
        }
    }
}

// ---------------------------------------------------------------------------
// gemm_bt: C(M x ncols) = A(M x K) @ B(ncols x K)^T + bias, bf16 MFMA
// (R4 structure: gload_lds width=16 both operands, BK=64, 128x128 tile,
//  4 waves 2x2, 16x16x32 MFMA, XCD-aware 1-D grid.) Used for GEMM2.
// ---------------------------------------------------------------------------
template <bool OUT_F32, bool FUSE_SM>
__global__ __launch_bounds__(256, 4)
void gemm_bt(const short* __restrict__ A, int lda,
             const short* __restrict__ B,           // (ncols x K) bf16 row-major
             const float* __restrict__ bias,
             void* __restrict__ Cp, int ldc,
             int M, int K, int clog2, int Rtiles) {
    __shared__ short As[128 * 64];
    __shared__ short Bs[128 * 64];

    const int id = blockIdx.x;
    const int xcd = id & 7;
    const int s = id >> 3;
    const int cblk = s & ((1 << clog2) - 1);
    const int slice = (Rtiles + 7) >> 3;
    const int rt = xcd * slice + (s >> clog2);
    if (rt >= Rtiles) return;

    const int tid = threadIdx.x;
    const int wid = tid >> 6, lane = tid & 63;
    const int col0 = cblk * 128;
    const int row0 = rt * 128;
    const int wm = (wid >> 1) * 64, wn = (wid & 1) * 64;
    const int lr = lane & 15, lq = lane >> 4;

    int st_row[4], st_kc[4];
    #pragma unroll
    for (int it = 0; it < 4; ++it) {
        int c = tid + it * 256;
        st_row[it] = c >> 3;
        st_kc[it] = (c & 7) ^ (st_row[it] & 7);
    }
    const int fx0 = (lq ^ (lr & 7)) * 8;
    const int fx1 = ((4 + lq) ^ (lr & 7)) * 8;

    floatx4 acc[4][4];
    #pragma unroll
    for (int i = 0; i < 4; ++i)
        #pragma unroll
        for (int j = 0; j < 4; ++j) acc[i][j] = (floatx4)(0.f);

    const short* Abase = A + (size_t)row0 * lda;
    const short* Bbase = B + (size_t)col0 * lda;

    for (int k0 = 0; k0 < K; k0 += 64) {
        #pragma unroll
        for (int it = 0; it < 4; ++it) {
            short* ldsA = As + (wid * 64 + it * 256) * 8;
            short* ldsB = Bs + (wid * 64 + it * 256) * 8;
            GLOAD_LDS16(Abase + (size_t)st_row[it] * lda + k0 + st_kc[it] * 8, ldsA);
            GLOAD_LDS16(Bbase + (size_t)st_row[it] * lda + k0 + st_kc[it] * 8, ldsB);
        }
        __syncthreads();

        short8 af[4], bfr[4];
        #pragma unroll
        for (int i = 0; i < 4; ++i) af[i]  = *(const short8*)&As[(wm + i * 16 + lr) * 64 + fx0];
        #pragma unroll
        for (int j = 0; j < 4; ++j) bfr[j] = *(const short8*)&Bs[(wn + j * 16 + lr) * 64 + fx0];
        #pragma unroll
        for (int i = 0; i < 4; ++i)
            #pragma unroll
            for (int j = 0; j < 4; ++j)
                acc[i][j] = __builtin_amdgcn_mfma_f32_16x16x32_bf16(af[i], bfr[j], acc[i][j], 0, 0, 0);
        #pragma unroll
        for (int i = 0; i < 4; ++i) af[i]  = *(const short8*)&As[(wm + i * 16 + lr) * 64 + fx1];
        #pragma unroll
        for (int j = 0; j < 4; ++j) bfr[j] = *(const short8*)&Bs[(wn + j * 16 + lr) * 64 + fx1];
        #pragma unroll
        for (int i = 0; i < 4; ++i)
            #pragma unroll
            for (int j = 0; j < 4; ++j)
                acc[i][j] = __builtin_amdgcn_mfma_f32_16x16x32_bf16(af[i], bfr[j], acc[i][j], 0, 0, 0);
        __syncthreads();
    }

    const bool do_sm = FUSE_SM && (col0 >= 512);
    float bcol[4];
    #pragma unroll
    for (int j = 0; j < 4; ++j) bcol[j] = bias[col0 + wn + j * 16 + lr];

    #pragma unroll
    for (int i = 0; i < 4; ++i) {
        #pragma unroll
        for (int r = 0; r < 4; ++r) {
            int grow = row0 + wm + i * 16 + lq * 4 + r;
            float v[4];
            #pragma unroll
            for (int j = 0; j < 4; ++j) v[j] = acc[i][j][r] + bcol[j];
            if (do_sm) {
                float m = fmaxf(fmaxf(v[0], v[1]), fmaxf(v[2], v[3]));
                #pragma unroll
                for (int off = 1; off < 16; off <<= 1) m = fmaxf(m, __shfl_xor(m, off));
                float sum = 0.f;
                #pragma unroll
                for (int j = 0; j < 4; ++j) { v[j] = __expf(v[j] - m); sum += v[j]; }
                #pragma unroll
                for (int off = 1; off < 16; off <<= 1) sum += __shfl_xor(sum, off);
                float inv = 1.f / sum;
                #pragma unroll
                for (int j = 0; j < 4; ++j) v[j] *= inv;
            }
            if (grow < M) {
                #pragma unroll
                for (int j = 0; j < 4; ++j) {
                    int gcol = col0 + wn + j * 16 + lr;
                    if constexpr (OUT_F32) ((float*)Cp)[(size_t)grow * ldc + gcol] = v[j];
                    else                   ((short*)Cp)[(size_t)grow * ldc + gcol] = f2bf(v[j]);
                }
            }
        }
    }
}

// ---------------------------------------------------------------------------
// attn: per head, G=64 tokens (unchanged)
// ---------------------------------------------------------------------------
__global__ __launch_bounds__(256)
void attn_kernel(const float* __restrict__ tok_raw, const float* __restrict__ norm,
                 const float* __restrict__ Wq, const float* __restrict__ Wk,
                 const float* __restrict__ Wv, const float* __restrict__ Wo,
                 float* __restrict__ out_tok) {
    const int h = blockIdx.x;
    const int tid = threadIdx.x;
    const int g = tid & 63, part = tid >> 6;
    const int o0 = part * 16;

    __shared__ float tk[64][65];
    __shared__ float qq[64][65];
    __shared__ float kk[64][65];
    __shared__ float vv[64][65];
    __shared__ float pp[64][65];
    __shared__ float od[64][65];

    const float inv = 1.f / (norm[h * 64 + g] + EPSF);
    #pragma unroll
    for (int dd = 0; dd < 16; ++dd) {
        int d = o0 + dd;
        tk[g][d] = tok_raw[(size_t)(h * 64 + g) * 64 + d] * inv;
    }
    __syncthreads();

    float t[64];
    #pragma unroll
    for (int d = 0; d < 64; ++d) t[d] = tk[g][d];
    #pragma unroll
    for (int oo = 0; oo < 16; ++oo) {
        int o = o0 + oo;
        float sq = 0.f, sk = 0.f, sv = 0.f;
        #pragma unroll
        for (int d = 0; d < 64; ++d) {
            float td = t[d];
            sq += td * Wq[o * 64 + d];
            sk += td * Wk[o * 64 + d];
            sv += td * Wv[o * 64 + d];
        }
        qq[g][o] = sq; kk[g][o] = sk; vv[g][o] = sv;
    }
    __syncthreads();

    float q[64];
    #pragma unroll
    for (int o = 0; o < 64; ++o) q[o] = qq[g][o];
    #pragma unroll
    for (int jj = 0; jj < 16; ++jj) {
        int j = o0 + jj;
        float s = 0.f;
        #pragma unroll
        for (int o = 0; o < 64; ++o) s += q[o] * kk[j][o];
        pp[g][j] = s * 0.125f;
    }
    __syncthreads();

    float sr[64];
    float mx = -1e30f;
    #pragma unroll
    for (int j = 0; j < 64; ++j) { sr[j] = pp[g][j]; mx = fmaxf(mx, sr[j]); }
    float sum = 0.f;
    #pragma unroll
    for (int j = 0; j < 64; ++j) { sr[j] = __expf(sr[j] - mx); sum += sr[j]; }
    const float isum = 1.f / sum;

    #pragma unroll
    for (int dd = 0; dd < 16; ++dd) {
        int d = o0 + dd;
        float a = 0.f;
        #pragma unroll
        for (int j = 0; j < 64; ++j) a += sr[j] * vv[j][d];
        od[g][d] = a * isum;
    }
    __syncthreads();

    float ot[64];
    #pragma unroll
    for (int d = 0; d < 64; ++d) ot[d] = od[g][d];
    #pragma unroll
    for (int oo = 0; oo < 16; ++oo) {
        int o = o0 + oo;
        float a = 0.f;
        #pragma unroll
        for (int d = 0; d < 64; ++d) a += ot[d] * Wo[o * 64 + d];
        out_tok[(size_t)(h * 64 + g) * 64 + o] = a;
    }
}

// ---------------------------------------------------------------------------
// fold2: V[o, h*64+g] = sum_d out_tok[h,g,d] * Wout[o, h*64+d]  (bf16 out)
// ---------------------------------------------------------------------------
__global__ void fold2_kernel(const float* __restrict__ out_tok,
                             const float* __restrict__ Wout, short* __restrict__ Vbf) {
    int idx = blockIdx.x * 256 + threadIdx.x;
    int o = idx >> 9, hg = idx & 511;
    int h = hg >> 6;
    const float* ot = out_tok + (size_t)hg * 64;
    const float* wo = Wout + (size_t)o * 512 + h * 64;
    float s = 0.f;
    #pragma unroll 8
    for (int d = 0; d < 64; ++d) s += ot[d] * wo[d];
    Vbf[idx] = f2bf(s);
}

// ---------------------------------------------------------------------------
extern "C" void kernel_launch(void* const* d_in, const int* in_sizes, int n_in,
                              void* d_out, int out_size, void* d_ws, size_t ws_size,
                              hipStream_t stream) {
    const float* x    = (const float*)d_in[0];
    const float* Wx   = (const float*)d_in[1];
    const float* bx   = (const float*)d_in[2];
    const float* Wfx  = (const float*)d_in[3];
    const float* bfx  = (const float*)d_in[4];
    const float* Ws   = (const float*)d_in[5];
    const float* bs   = (const float*)d_in[6];
    const float* temp = (const float*)d_in[7];
    const float* Wq   = (const float*)d_in[8];
    const float* Wk   = (const float*)d_in[9];
    const float* Wv   = (const float*)d_in[10];
    const float* Wo   = (const float*)d_in[11];
    const float* Wout = (const float*)d_in[12];
    const float* bout = (const float*)d_in[13];

    const int N = in_sizes[0] / HID;

    char* p = (char*)d_ws;
    short* w_bf = (short*)p;          p += (size_t)N * 512 * 2;        // softmax weights
    short* Wcat = (short*)p;          p += (size_t)1024 * 512 * 2;
    float* bias_cat = (float*)p;      p += 1024 * 4;
    float* tok_raw = (float*)p;       p += (size_t)NH * GG * DD * 4;   // contiguous with norm
    float* norm_ = (float*)p;         p += (size_t)NH * GG * 4;
    float* out_tok = (float*)p;       p += (size_t)NH * GG * DD * 4;
    short* Vbf = (short*)p;           p += (size_t)512 * 512 * 2;

    fold1_kernel<<<2048, 256, 0, stream>>>(Wx, bx, Wfx, bfx, Ws, bs, temp, Wcat, bias_cat);
    hipMemsetAsync(tok_raw, 0, (size_t)(NH * GG * DD + NH * GG) * 4, stream);

    const int R = (N + 127) / 128;       // 782 row tiles
    const int slice = (R + 7) / 8;       // 98

    // GEMM1 + cast + softmax + pool fused: 4 head-pair col-blocks
    gemm1_pool<<<8 * slice * 4, 512, 0, stream>>>(
        x, Wcat, bias_cat, w_bf, tok_raw, norm_, N, R);

    attn_kernel<<<8, 256, 0, stream>>>(tok_raw, norm_, Wq, Wk, Wv, Wo, out_tok);

    fold2_kernel<<<1024, 256, 0, stream>>>(out_tok, Wout, Vbf);

    // GEMM2: A = dense w_bf (lda 512), 4 col tiles, output f32 + bout
    gemm_bt<true, false><<<8 * slice * 4, 256, 0, stream>>>(
        w_bf, 512, Vbf, bout, d_out, HID, N, 512, 2, R);
}